// Round 7
// baseline (74.012 us; speedup 1.0000x reference)
//
#include <hip/hip_runtime.h>
#include <math.h>

namespace {
constexpr int kB = 256;
constexpr int kT = 64;
constexpr int kPhys = 3;
constexpr int kLat = 8;
constexpr int kNN = 128;
constexpr int kWin = 32;
constexpr int kPred = 64;
constexpr int kHRow = 132;       // padded f32 activation row (stride%32==4 -> 2-way banks)
constexpr int kDecRows = 96;     // 64 (x_ae) + 32 (new y_adv rows)
constexpr int kThreads = 1024;
constexpr int kWUnit = 8 * 4 * 64 * 8;  // 16384 shorts per weight plane-unit
}

typedef short bf16x8 __attribute__((ext_vector_type(8)));
typedef float f32x4 __attribute__((ext_vector_type(4)));

__device__ __forceinline__ double rdlane_f64(double x, int l) {
  const long long v = __double_as_longlong(x);
  const int lo = __builtin_amdgcn_readlane((int)(unsigned int)(v & 0xffffffffll), l);
  const int hi = __builtin_amdgcn_readlane((int)(v >> 32), l);
  const long long r = (((long long)hi) << 32) | (unsigned long long)(unsigned int)lo;
  return __longlong_as_double(r);
}

__device__ __forceinline__ unsigned rneb(float f) {  // f32 -> bf16 bits (RNE)
  const unsigned u = __float_as_uint(f);
  return (u + 0x7fffu + ((u >> 16) & 1u)) >> 16;
}
// 3-way split: a ~= b1+b2+b3 with O(2^-25)|a| error (f32-equivalent products)
__device__ __forceinline__ void split3(float a, short& s1, short& s2, short& s3) {
  const unsigned b1 = rneb(a);
  const float f1 = __uint_as_float(b1 << 16);
  const float r1 = a - f1;
  const unsigned b2 = rneb(r1);
  const float f2 = __uint_as_float(b2 << 16);
  s1 = (short)b1; s2 = (short)b2; s3 = (short)rneb(r1 - f2);
}
// 2-way split (decoder-only; terminal outputs). Matches first two of split3.
__device__ __forceinline__ void split2(float a, short& s1, short& s2) {
  const unsigned b1 = rneb(a);
  const float f1 = __uint_as_float(b1 << 16);
  s1 = (short)b1; s2 = (short)rneb(a - f1);
}

// ---- prologue: split hidden weights into B-fragment planes (launch-invariant) ----
__global__ __launch_bounds__(256) void split_weights_kernel(
    const float* __restrict__ ewh, const float* __restrict__ dwh,
    short* __restrict__ wfrag)
{
  const int gid = blockIdx.x * 256 + threadIdx.x;  // 12288 = 6 layers x 8n x 4q x 64l
  const int l = gid & 63;
  const int q = (gid >> 6) & 3;
  const int n = (gid >> 8) & 7;
  const int layer = gid >> 11;  // 0..5
  const bool enc = layer < 3;
  const float* __restrict__ W = enc ? (ewh + (size_t)layer * kNN * kNN)
                                    : (dwh + (size_t)(layer - 3) * kNN * kNN);
  const int colg = 16 * n + (l & 15);
  const int krow = 8 * (l >> 4);
  bf16x8 p1, p2, p3;
#pragma unroll
  for (int e = 0; e < 8; ++e) {
    const float wv = W[(32 * q + krow + e) * kNN + colg];
    short s1, s2, s3; split3(wv, s1, s2, s3);
    p1[e] = s1; p2[e] = s2; p3[e] = s3;
  }
  const int off = ((n * 4 + q) * 64 + l) * 8;
  if (enc) {
    const size_t base = (size_t)(layer * 3) * kWUnit;
    *(bf16x8*)&wfrag[base + off] = p1;
    *(bf16x8*)&wfrag[base + kWUnit + off] = p2;
    *(bf16x8*)&wfrag[base + 2 * kWUnit + off] = p3;
  } else {
    const size_t base = (size_t)(9 + (layer - 3) * 2) * kWUnit;
    *(bf16x8*)&wfrag[base + off] = p1;
    *(bf16x8*)&wfrag[base + kWUnit + off] = p2;
  }
}

// ---- one hidden layer 128->128 (+relu): direct per-lane A-read from hsrc,
//      in-register split, MFMA, write to hdst (ping-pong; no pack phase) ----
template<int MPW, int SPLITS>
__device__ __forceinline__ void mfma_layer_direct(
    const short* __restrict__ Bfrag, const float* __restrict__ bias,
    const float* __restrict__ hsrc, float* __restrict__ hdst, int tid)
{
  const int w = tid >> 6, l = tid & 63;
  const int n = w & 7, m0 = (w >> 3) * MPW;
  const int colg = 16 * n + (l & 15);
  bf16x8 B1[4], B2[4], B3[4];
#pragma unroll
  for (int q = 0; q < 4; ++q) {
    const int boff = ((n * 4 + q) * 64 + l) * 8;
    B1[q] = *(const bf16x8*)&Bfrag[boff];
    B2[q] = *(const bf16x8*)&Bfrag[kWUnit + boff];
    if constexpr (SPLITS == 3) B3[q] = *(const bf16x8*)&Bfrag[2 * kWUnit + boff];
  }
  const float bj = bias[colg];
  f32x4 acc[MPW];
#pragma unroll
  for (int mi = 0; mi < MPW; ++mi) acc[mi] = {bj, bj, bj, bj};
  const int arow = l & 15;
  const int acolb = 8 * (l >> 4);
#pragma unroll
  for (int q = 0; q < 4; ++q) {
#pragma unroll
    for (int mi = 0; mi < MPW; ++mi) {
      const float* __restrict__ ap = &hsrc[(16 * (m0 + mi) + arow) * kHRow + 32 * q + acolb];
      const float4 f0 = *(const float4*)ap;
      const float4 f1 = *(const float4*)(ap + 4);
      const float f[8] = {f0.x, f0.y, f0.z, f0.w, f1.x, f1.y, f1.z, f1.w};
      bf16x8 a1, a2, a3;
#pragma unroll
      for (int e = 0; e < 8; ++e) {
        if constexpr (SPLITS == 3) {
          short s1, s2, s3; split3(f[e], s1, s2, s3);
          a1[e] = s1; a2[e] = s2; a3[e] = s3;
        } else {
          short s1, s2; split2(f[e], s1, s2);
          a1[e] = s1; a2[e] = s2;
        }
      }
      acc[mi] = __builtin_amdgcn_mfma_f32_16x16x32_bf16(a1, B1[q], acc[mi], 0, 0, 0);
      acc[mi] = __builtin_amdgcn_mfma_f32_16x16x32_bf16(a1, B2[q], acc[mi], 0, 0, 0);
      acc[mi] = __builtin_amdgcn_mfma_f32_16x16x32_bf16(a2, B1[q], acc[mi], 0, 0, 0);
      if constexpr (SPLITS == 3) {
        acc[mi] = __builtin_amdgcn_mfma_f32_16x16x32_bf16(a1, B3[q], acc[mi], 0, 0, 0);
        acc[mi] = __builtin_amdgcn_mfma_f32_16x16x32_bf16(a2, B2[q], acc[mi], 0, 0, 0);
        acc[mi] = __builtin_amdgcn_mfma_f32_16x16x32_bf16(a3, B1[q], acc[mi], 0, 0, 0);
      }
    }
  }
  const int rbase = (l >> 4) * 4;
#pragma unroll
  for (int mi = 0; mi < MPW; ++mi)
#pragma unroll
    for (int r = 0; r < 4; ++r)
      hdst[(16 * (m0 + mi) + rbase + r) * kHRow + colg] = fmaxf(acc[mi][r], 0.f);
}

__global__ __launch_bounds__(kThreads, 4) void fused_kernel(
    const float* __restrict__ x,
    const float* __restrict__ ewin, const float* __restrict__ ebin,
    const float* __restrict__ ebh,
    const float* __restrict__ ewout,const float* __restrict__ ebout,
    const float* __restrict__ dwin, const float* __restrict__ dbin,
    const float* __restrict__ dbh,
    const float* __restrict__ dwout,const float* __restrict__ dbout,
    const short* __restrict__ wfrag,
    float* __restrict__ y_g, float* __restrict__ xae_g,
    float* __restrict__ xadv_g, float* __restrict__ yadv_g)
{
  __shared__ __align__(16) float hbA[kDecRows * kHRow];  // 50688 B (also DMD f64 scratch)
  __shared__ __align__(16) float hbB[kDecRows * kHRow];  // 50688 B
  __shared__ float ybuf[kT][kLat + 1];
  __shared__ float yadv2[kWin][kLat + 1];
  __shared__ float inb[kT][4];

  double* dmd = (double*)hbA;
  double* yd   = dmd;           // [8][65]
  double* P    = dmd + 520;     // [32][67]
  double* Corr = dmd + 2664;    // [32][33]
  double* KTm  = dmd + 3720;    // [31][33]
  double* Dv   = dmd + 4743;    // [32][33]

  const int tid = threadIdx.x;
  const int b = blockIdx.x;

  // ---- load x ----
  const float* __restrict__ xg = x + (size_t)b * kT * kPhys;
  for (int i = tid; i < kT * kPhys; i += kThreads) inb[i / 3][i % 3] = xg[i];
  __syncthreads();

  // ---- encoder input layer 3 -> 128 -> hbA ----
  {
    const int j = tid & 127, rg = tid >> 7;  // rg 0..7, 8 rows each
    const float w0 = ewin[j], w1 = ewin[kNN + j], w2 = ewin[2 * kNN + j];
    const float bj = ebin[j];
#pragma unroll
    for (int rr = 0; rr < 8; ++rr) {
      const int r = rg * 8 + rr;
      hbA[r * kHRow + j] = fmaxf(bj + inb[r][0] * w0 + inb[r][1] * w1 + inb[r][2] * w2, 0.f);
    }
  }
  __syncthreads();

  // ---- encoder hidden layers (3-split, f32-exact), ping-pong A<->B ----
  mfma_layer_direct<2, 3>(wfrag + (size_t)0 * kWUnit, ebh + 0 * kNN, hbA, hbB, tid);
  __syncthreads();
  mfma_layer_direct<2, 3>(wfrag + (size_t)3 * kWUnit, ebh + 1 * kNN, hbB, hbA, tid);
  __syncthreads();
  mfma_layer_direct<2, 3>(wfrag + (size_t)6 * kWUnit, ebh + 2 * kNN, hbA, hbB, tid);
  __syncthreads();

  // ---- encoder output layer 128 -> 8 (reads hbB; fills yd in hbA) ----
  if (tid < 512) {
    const int r = tid >> 3, o = tid & 7;
    float a = ebout[o];
    for (int k4 = 0; k4 < kNN; k4 += 4) {
      const float4 hv = *(const float4*)&hbB[r * kHRow + k4];
      a += hv.x * ewout[(k4 + 0) * kLat + o] + hv.y * ewout[(k4 + 1) * kLat + o]
         + hv.z * ewout[(k4 + 2) * kLat + o] + hv.w * ewout[(k4 + 3) * kLat + o];
    }
    ybuf[r][o] = a;
    y_g[(size_t)b * kT * kLat + tid] = a;
    yd[o * 65 + r] = (double)a;
  }
  __syncthreads();

  // ---- Hankel-DMD (f64, exact-math rewrite; scratch in hbA) ----
  {
    for (int idx = tid; idx < 32 * 64; idx += kThreads) {
      const int d = idx >> 6, t = idx & 63;
      if (t + d < kT) {
        double s = 0.0;
#pragma unroll
        for (int l = 0; l < kLat; ++l) s += yd[l * 65 + t] * yd[l * 65 + t + d];
        P[d * 67 + t] = s;
      }
    }
    __syncthreads();

    {
      const int a = tid >> 5, c = tid & 31;
      const int d = (c >= a) ? (c - a) : (a - c);
      const int base = (c >= a) ? a : c;
      double s0 = 0.0, s1 = 0.0;
#pragma unroll
      for (int r = 0; r < 32; r += 2) { s0 += P[d * 67 + base + r]; s1 += P[d * 67 + base + r + 1]; }
      Corr[a * 33 + c] = s0 + s1 + P[d * 67 + base + 32];
    }
    __syncthreads();

    // single-wave register Gauss-Jordan [G|C] -> [I|K], then power iteration
    if (tid < 64) {
      const int lane = tid;
      const int colidx = (lane <= 30) ? lane : (lane <= 61 ? lane - 30 : 1);
      double m[31];
#pragma unroll
      for (int i = 0; i < 31; ++i) m[i] = Corr[i * 33 + colidx];
#pragma unroll
      for (int k = 0; k < 31; ++k) {
        const double piv = rdlane_f64(m[k], k);
        const double pinv = 1.0 / piv;
        m[k] *= pinv;
#pragma unroll
        for (int i = 0; i < 31; ++i) {
          if (i == k) continue;
          const double bci = rdlane_f64(m[i], k);
          m[i] = fma(-bci, m[k], m[i]);
        }
      }
      if (lane >= 31 && lane < 62) {
        const int c = lane - 31;
#pragma unroll
        for (int i = 0; i < 31; ++i) KTm[i * 33 + c] = m[i];
      }
      const int ri = (lane < 31) ? lane : 0;
      double Kr[31];
#pragma unroll
      for (int j = 0; j < 31; ++j) Kr[j] = KTm[ri * 33 + j];

      double dv = Kr[30];  // d_0 = K[:,30]
      if (lane < 31) Dv[0 * 33 + lane] = dv;
      for (int k = 0; k < 31; ++k) {
        double a0 = 0.0, a1 = 0.0, a2 = 0.0, a3 = 0.0;
#pragma unroll
        for (int j = 0; j < 31; ++j) {
          const double dj = rdlane_f64(dv, j);
          if ((j & 3) == 0) a0 = fma(Kr[j], dj, a0);
          else if ((j & 3) == 1) a1 = fma(Kr[j], dj, a1);
          else if ((j & 3) == 2) a2 = fma(Kr[j], dj, a2);
          else a3 = fma(Kr[j], dj, a3);
        }
        dv = (a0 + a1) + (a2 + a3);
        if (lane < 31) Dv[(k + 1) * 33 + lane] = dv;
      }
    }
    __syncthreads();

    float* __restrict__ ob = yadv_g + (size_t)b * kPred * kLat;
    if (tid < 256) {
      ob[tid] = ybuf[tid >> 3][tid & 7];  // p < 32: exact copy of y
    } else if (tid < 512) {
      const int q = tid - 256;
      const int k = q >> 3, l = q & 7;
      double a0 = 0.0, a1 = 0.0, a2 = 0.0, a3 = 0.0;
#pragma unroll
      for (int j = 0; j < 31; ++j) {
        const double t = yd[l * 65 + j + 1];
        if ((j & 3) == 0) a0 = fma(t, Dv[k * 33 + j], a0);
        else if ((j & 3) == 1) a1 = fma(t, Dv[k * 33 + j], a1);
        else if ((j & 3) == 2) a2 = fma(t, Dv[k * 33 + j], a2);
        else a3 = fma(t, Dv[k * 33 + j], a3);
      }
      const float v = (float)((a0 + a1) + (a2 + a3));
      ob[256 + q] = v;
      yadv2[k][l] = v;
    }
    __syncthreads();  // yd/Dv dead; hbA free for decoder
  }

  // ---- decoder input layer 8 -> 128, 96 rows -> hbA ----
  {
    const int j = tid & 127, rg = tid >> 7;  // 12 rows each
    float wr[kLat];
#pragma unroll
    for (int k = 0; k < kLat; ++k) wr[k] = dwin[k * kNN + j];
    const float bj = dbin[j];
#pragma unroll
    for (int rr = 0; rr < 12; ++rr) {
      const int r = rg * 12 + rr;
      const float* __restrict__ src = (r < kT) ? &ybuf[r][0] : &yadv2[r - kT][0];
      float a = bj;
#pragma unroll
      for (int k = 0; k < kLat; ++k) a += src[k] * wr[k];
      hbA[r * kHRow + j] = fmaxf(a, 0.f);
    }
  }
  __syncthreads();

  // ---- decoder hidden layers (2-split, 3 products; terminal path) ----
  mfma_layer_direct<3, 2>(wfrag + (size_t)9  * kWUnit, dbh + 0 * kNN, hbA, hbB, tid);
  __syncthreads();
  mfma_layer_direct<3, 2>(wfrag + (size_t)11 * kWUnit, dbh + 1 * kNN, hbB, hbA, tid);
  __syncthreads();
  mfma_layer_direct<3, 2>(wfrag + (size_t)13 * kWUnit, dbh + 2 * kNN, hbA, hbB, tid);
  __syncthreads();

  // ---- decoder output layer 128 -> 3 (reads hbB) ----
  for (int idx = tid; idx < kDecRows * kPhys; idx += kThreads) {
    const int r = idx / 3, o = idx - r * 3;
    float a = dbout[o];
    for (int k4 = 0; k4 < kNN; k4 += 4) {
      const float4 hv = *(const float4*)&hbB[r * kHRow + k4];
      a += hv.x * dwout[(k4 + 0) * kPhys + o] + hv.y * dwout[(k4 + 1) * kPhys + o]
         + hv.z * dwout[(k4 + 2) * kPhys + o] + hv.w * dwout[(k4 + 3) * kPhys + o];
    }
    if (r < kT) {
      xae_g[(size_t)b * kT * kPhys + idx] = a;
      if (r < kWin) xadv_g[(size_t)b * kT * kPhys + idx] = a;
    } else {
      const int rr = r - kT + kWin;  // 32..63
      xadv_g[(size_t)b * kT * kPhys + rr * kPhys + o] = a;
    }
  }
}

extern "C" void kernel_launch(void* const* d_in, const int* in_sizes, int n_in,
                              void* d_out, int out_size, void* d_ws, size_t ws_size,
                              hipStream_t stream)
{
  const float* x         = (const float*)d_in[0];
  const float* enc_w_in  = (const float*)d_in[1];
  const float* enc_b_in  = (const float*)d_in[2];
  const float* enc_w_h   = (const float*)d_in[3];
  const float* enc_b_h   = (const float*)d_in[4];
  const float* enc_w_out = (const float*)d_in[5];
  const float* enc_b_out = (const float*)d_in[6];
  const float* dec_w_in  = (const float*)d_in[7];
  const float* dec_b_in  = (const float*)d_in[8];
  const float* dec_w_h   = (const float*)d_in[9];
  const float* dec_b_h   = (const float*)d_in[10];
  const float* dec_w_out = (const float*)d_in[11];
  const float* dec_b_out = (const float*)d_in[12];

  float* out   = (float*)d_out;
  float* y     = out;                                  // (B,T,8)   131072
  float* x_ae  = out + (size_t)kB * kT * kLat;         // (B,T,3)    49152
  float* x_adv = x_ae + (size_t)kB * kT * kPhys;       // (B,T,3)    49152
  float* y_adv = x_adv + (size_t)kB * kT * kPhys;      // (B,64,8)  131072

  short* wfrag = (short*)d_ws;   // 15 units x 16384 shorts = 491520 B

  split_weights_kernel<<<48, 256, 0, stream>>>(enc_w_h, dec_w_h, wfrag);
  fused_kernel<<<kB, kThreads, 0, stream>>>(
      x, enc_w_in, enc_b_in, enc_b_h, enc_w_out, enc_b_out,
      dec_w_in, dec_b_in, dec_b_h, dec_w_out, dec_b_out,
      wfrag, y, x_ae, x_adv, y_adv);
}